// Round 2
// baseline (88743.951 us; speedup 1.0000x reference)
//
#include <hip/hip_runtime.h>
#include <math.h>

#define NL 10
#define C 128
#define CS 256
#define NV 256
#define NB 32
#define TT 1024
#define WPC 8
#define NTHR 256
#define CH_BYTES 131072  // bytes of exchange state per chain

typedef unsigned long long ull;

// ---------------- atomic helpers (agent scope, relaxed) ---------------------------
__device__ __forceinline__ ull aLoad64(const ull* p) {
  return __hip_atomic_load(p, __ATOMIC_RELAXED, __HIP_MEMORY_SCOPE_AGENT);
}
__device__ __forceinline__ void aStore64(ull* p, ull v) {
  __hip_atomic_store(p, v, __ATOMIC_RELAXED, __HIP_MEMORY_SCOPE_AGENT);
}
__device__ __forceinline__ ull packF(float x, unsigned tag) {
  return ((ull)__float_as_uint(x) << 32) | (ull)tag;
}
__device__ __forceinline__ float unpackF(ull v) {
  return __uint_as_float((unsigned)(v >> 32));
}

// ---------------- K1: embedding lookup ------------------------------------------
__global__ __launch_bounds__(256) void k_embed(const int* __restrict__ prompt,
                                               const float* __restrict__ E,
                                               float* __restrict__ X) {
  int idx = blockIdx.x * 256 + threadIdx.x;
  const float4* E4 = (const float4*)E;
  float4* X4 = (float4*)X;
#pragma unroll
  for (int p = 0; p < 4; ++p) {
    int i = idx + p * 262144;
    int row = i >> 5, c4 = i & 31;
    int tk = prompt[row];
    X4[i] = E4[tk * 32 + c4];
  }
}

// ---------------- K2: one dilated residual layer over full prompt ----------------
__global__ __launch_bounds__(256) void k_layer(
    const float* __restrict__ Xin, float* __restrict__ Xout,
    const float* __restrict__ Wf, const float* __restrict__ Wg,
    const float* __restrict__ bf, const float* __restrict__ bg,
    const float* __restrict__ Wres, const float* __restrict__ bres,
    ull* __restrict__ rings, float* __restrict__ zlast, int l) {
  const int tid = threadIdx.x;
  const int m = blockIdx.x;
  const int b = m >> 3;
  const int t0 = (m & 7) << 7;
  const int d = 1 << l;

  __shared__ __align__(16) float sm[12416];
  float* Axd = sm;                // [16][132]
  float* Ax  = sm + 16 * 132;
  float* Wfs = sm + 32 * 132;     // [16][256]
  float* Wgs = Wfs + 16 * 256;

  const int rg = tid >> 4, cg = tid & 15;

  float af[8][8] = {};
  float ag[8][8] = {};

  for (int kc = 0; kc < 8; ++kc) {
    __syncthreads();
#pragma unroll
    for (int p = 0; p < 2; ++p) {
      int li = tid + p * 256;
      int row = li >> 2, c4 = li & 3;
      int ci = kc * 16 + c4 * 4;
      int t = t0 + row;
      float4 vx = *(const float4*)(Xin + ((size_t)b * TT + t) * C + ci);
      float4 vd = make_float4(0.f, 0.f, 0.f, 0.f);
      int ts = t - d;
      if (ts >= 0) vd = *(const float4*)(Xin + ((size_t)b * TT + ts) * C + ci);
      Ax[(c4 * 4 + 0) * 132 + row] = vx.x;
      Ax[(c4 * 4 + 1) * 132 + row] = vx.y;
      Ax[(c4 * 4 + 2) * 132 + row] = vx.z;
      Ax[(c4 * 4 + 3) * 132 + row] = vx.w;
      Axd[(c4 * 4 + 0) * 132 + row] = vd.x;
      Axd[(c4 * 4 + 1) * 132 + row] = vd.y;
      Axd[(c4 * 4 + 2) * 132 + row] = vd.z;
      Axd[(c4 * 4 + 3) * 132 + row] = vd.w;
    }
#pragma unroll
    for (int p = 0; p < 4; ++p) {
      int li = tid + p * 256;
      int ci = li >> 6, cc = (li & 63) << 2;
      size_t off = ((size_t)(l * C + kc * 16 + ci) * C) * 2 + cc;
      *(float4*)&Wfs[ci * 256 + cc] = *(const float4*)(Wf + off);
      *(float4*)&Wgs[ci * 256 + cc] = *(const float4*)(Wg + off);
    }
    __syncthreads();
    for (int ci = 0; ci < 16; ++ci) {
      float4 d0 = *(float4*)&Axd[ci * 132 + rg * 8];
      float4 d1 = *(float4*)&Axd[ci * 132 + rg * 8 + 4];
      float4 x0 = *(float4*)&Ax[ci * 132 + rg * 8];
      float4 x1 = *(float4*)&Ax[ci * 132 + rg * 8 + 4];
      float axd[8] = {d0.x, d0.y, d0.z, d0.w, d1.x, d1.y, d1.z, d1.w};
      float ax[8]  = {x0.x, x0.y, x0.z, x0.w, x1.x, x1.y, x1.z, x1.w};
#pragma unroll
      for (int jj = 0; jj < 4; ++jj) {
        float4 wf = *(float4*)&Wfs[ci * 256 + cg * 16 + jj * 4];
        float4 wg = *(float4*)&Wgs[ci * 256 + cg * 16 + jj * 4];
#pragma unroll
        for (int i = 0; i < 8; ++i) {
          af[i][2 * jj]     += axd[i] * wf.x + ax[i] * wf.y;
          af[i][2 * jj + 1] += axd[i] * wf.z + ax[i] * wf.w;
          ag[i][2 * jj]     += axd[i] * wg.x + ax[i] * wg.y;
          ag[i][2 * jj + 1] += axd[i] * wg.z + ax[i] * wg.w;
        }
      }
    }
  }

  float bfv[8], bgv[8];
#pragma unroll
  for (int j = 0; j < 8; ++j) {
    bfv[j] = bf[l * C + cg * 8 + j];
    bgv[j] = bg[l * C + cg * 8 + j];
  }
#pragma unroll
  for (int i = 0; i < 8; ++i)
#pragma unroll
    for (int j = 0; j < 8; ++j) {
      float fv = tanhf(af[i][j] + bfv[j]);
      float gv = 1.f / (1.f + expf(-(ag[i][j] + bgv[j])));
      af[i][j] = fv * gv;
    }
  if (((m & 7) == 7) && rg == 15) {
#pragma unroll
    for (int j = 0; j < 8; ++j)
      zlast[((size_t)l * NB + b) * C + cg * 8 + j] = af[7][j];
  }
#pragma unroll
  for (int i = 0; i < 8; ++i)
#pragma unroll
    for (int j = 0; j < 8; ++j) ag[i][j] = 0.f;

  float* zs  = sm;
  float* Wrs = sm + 32 * 132;
  for (int c = 0; c < 4; ++c) {
    __syncthreads();
    if ((cg >> 2) == c) {
      int kl = (cg & 3) * 8;
#pragma unroll
      for (int i = 0; i < 8; ++i)
#pragma unroll
        for (int j = 0; j < 8; ++j) zs[(kl + j) * 132 + rg * 8 + i] = af[i][j];
    }
#pragma unroll
    for (int p = 0; p < 4; ++p) {
      int li = tid + p * 256;
      int kr = li >> 5, cc = (li & 31) << 2;
      *(float4*)&Wrs[kr * 128 + cc] =
          *(const float4*)(Wres + ((size_t)(l * C + c * 32 + kr)) * C + cc);
    }
    __syncthreads();
    for (int k = 0; k < 32; ++k) {
      float4 a0 = *(float4*)&zs[k * 132 + rg * 8];
      float4 a1 = *(float4*)&zs[k * 132 + rg * 8 + 4];
      float4 w0 = *(float4*)&Wrs[k * 128 + cg * 8];
      float4 w1 = *(float4*)&Wrs[k * 128 + cg * 8 + 4];
      float a[8] = {a0.x, a0.y, a0.z, a0.w, a1.x, a1.y, a1.z, a1.w};
      float wv[8] = {w0.x, w0.y, w0.z, w0.w, w1.x, w1.y, w1.z, w1.w};
#pragma unroll
      for (int i = 0; i < 8; ++i)
#pragma unroll
        for (int j = 0; j < 8; ++j) ag[i][j] += a[i] * wv[j];
    }
  }

  float brv[8];
#pragma unroll
  for (int j = 0; j < 8; ++j) brv[j] = bres[l * C + cg * 8 + j];
#pragma unroll
  for (int i = 0; i < 8; ++i) {
    int t = t0 + rg * 8 + i;
    const float4* xi = (const float4*)(Xin + ((size_t)b * TT + t) * C + cg * 8);
    float4 v0 = xi[0], v1 = xi[1];
    float o[8] = {v0.x, v0.y, v0.z, v0.w, v1.x, v1.y, v1.z, v1.w};
#pragma unroll
    for (int j = 0; j < 8; ++j) o[j] += brv[j] + ag[i][j];
    float4* xo = (float4*)(Xout + ((size_t)b * TT + t) * C + cg * 8);
    xo[0] = make_float4(o[0], o[1], o[2], o[3]);
    xo[1] = make_float4(o[4], o[5], o[6], o[7]);
    if (t >= TT - d) {
      int slot = t - (TT - d);
      ull* rp = rings + (size_t)(d - 1) * NB * C + ((size_t)slot * NB + b) * C + cg * 8;
      float vin[8] = {v0.x, v0.y, v0.z, v0.w, v1.x, v1.y, v1.z, v1.w};
#pragma unroll
      for (int j = 0; j < 8; ++j) rp[j] = packF(vin[j], 0u);  // prompt tag = 0
    }
  }
}

// ---------------- K3: skips@T-1 + head -> tok0 -----------------------------------
__global__ __launch_bounds__(256) void k_head0(
    const float* __restrict__ zlast, const float* __restrict__ Wskip,
    const float* __restrict__ bskip, const float* __restrict__ Wo1,
    const float* __restrict__ bo1, const float* __restrict__ Wo2,
    const float* __restrict__ bo2, char* __restrict__ chst,
    int* __restrict__ dout, int ostride) {
  int b = blockIdx.x, tid = threadIdx.x;
  __shared__ float zl[NL][C];
  __shared__ float sr[CS];
  __shared__ float h1[CS];
  __shared__ float lg[NV];
#pragma unroll
  for (int p = 0; p < 5; ++p) {
    int li = tid + p * 256;
    zl[li >> 7][li & 127] = zlast[((size_t)(li >> 7) * NB + b) * C + (li & 127)];
  }
  __syncthreads();
  float s = 0.f;
  for (int l = 0; l < NL; ++l) {
    s += bskip[l * CS + tid];
    const float* wp = Wskip + (size_t)(l * C) * CS + tid;
    for (int k = 0; k < C; ++k) s += zl[l][k] * wp[(size_t)k * CS];
  }
  sr[tid] = fmaxf(s, 0.f);
  __syncthreads();
  float h = bo1[tid];
  {
    const float* wp = Wo1 + tid;
    for (int k = 0; k < CS; ++k) h += sr[k] * wp[(size_t)k * CS];
  }
  h1[tid] = fmaxf(h, 0.f);
  __syncthreads();
  float lv = bo2[tid];
  {
    const float* wp = Wo2 + tid;
    for (int k = 0; k < CS; ++k) lv += h1[k] * wp[(size_t)k * NV];
  }
  lg[tid] = lv;
  __syncthreads();
  if (tid == 0) {
    float bv = lg[0]; int bi = 0;
    for (int v = 1; v < NV; ++v)
      if (lg[v] > bv) { bv = lg[v]; bi = v; }
    *(unsigned*)(chst + (size_t)b * CH_BYTES) = (unsigned)bi;  // tok0
    dout[(size_t)b * ostride + TT] = bi;
  }
}

// ---------------- K4: copy prompt into output ------------------------------------
__global__ __launch_bounds__(256) void k_copyprompt(const int* __restrict__ prompt,
                                                    int* __restrict__ dout,
                                                    int ostride) {
  int idx = blockIdx.x * 256 + threadIdx.x;
  int b = idx >> 10, t = idx & 1023;
  dout[(size_t)b * ostride + t] = prompt[idx];
}

// ---------------- K5: persistent decode (self-tagged dataflow) --------------------
// 32 chains x 8 WGs. WG w owns gate channels [16w,16w+16) and head cols [32w,32w+32).
// All cross-WG data is (float<<32 | step_tag) u64, poll-until-exact-tag.
__global__ __launch_bounds__(NTHR, 1) void k_decode(
    const float* __restrict__ E, const float* __restrict__ Wf,
    const float* __restrict__ Wg, const float* __restrict__ bf,
    const float* __restrict__ bg, const float* __restrict__ Wres,
    const float* __restrict__ bres, const float* __restrict__ Wskip,
    const float* __restrict__ bskip, const float* __restrict__ Wo1,
    const float* __restrict__ bo1, const float* __restrict__ Wo2,
    const float* __restrict__ bo2, ull* __restrict__ rings,
    char* __restrict__ chst, int* __restrict__ dout, int ostride) {
  const int tid = threadIdx.x;
  const int chain = blockIdx.x & 31;   // blockIdx%8 -> XCD: chain's 8 WGs co-XCD
  const int w = blockIdx.x >> 5;
  const int nsteps = ostride - TT;

  char* cb = chst + (size_t)chain * CH_BYTES;
  ull* xp  = (ull*)(cb + 1024);    // [9][8][128]
  ull* skp = (ull*)(cb + 74752);   // [8][256]
  ull* h1p = (ull*)(cb + 91136);   // [8][32]
  ull* amx = (ull*)(cb + 93184);   // [8]

  __shared__ float past[NL][C];
  __shared__ float xx[C];
  __shared__ float fred[16][17];
  __shared__ float gred[16][17];
  __shared__ float zbuf[16];
  __shared__ float skipr[CS];
  __shared__ float h1f[CS];
  __shared__ float hred[32][9];
  __shared__ float lgt[32];
  __shared__ ull am[8];
  __shared__ float bfl[NL][16], bgl[NL][16];
  __shared__ float brl[NL - 1][C];
  __shared__ float bsum[CS];

  // ---- bias preloads ----
  for (int li = tid; li < NL * 16; li += NTHR) {
    bfl[li >> 4][li & 15] = bf[(li >> 4) * C + w * 16 + (li & 15)];
    bgl[li >> 4][li & 15] = bg[(li >> 4) * C + w * 16 + (li & 15)];
  }
  for (int li = tid; li < (NL - 1) * C; li += NTHR)
    brl[li >> 7][li & 127] = bres[(li >> 7) * C + (li & 127)];
  {
    float sacc = 0.f;
    for (int l = 0; l < NL; ++l) sacc += bskip[l * CS + tid];
    bsum[tid] = sacc;
  }

  unsigned tok = *(const unsigned*)cb;  // tok0 from k_head0

  const int col = tid & 15, kg = tid >> 4;
  const int hj = tid & 31, hkg = tid >> 5;

  // loop-carried prefetch state (all indices compile-time under unroll)
  float2 gwf[2][8], gwg[2][8];
  float wresr[2][16], wskipr[2][16];
  float pfp[2], pgp[2];

  auto ringLoad = [&](int s2) {
#pragma unroll
    for (int p = 0; p < 5; ++p) {
      int li = tid + p * NTHR;
      int lp = li >> 7, cc = li & 127;
      int D = 1 << lp;
      int slot = s2 & (D - 1);
      unsigned expv = (s2 >= D) ? (unsigned)(s2 - D + 1) : 0u;
      const ull* rp =
          rings + (size_t)(D - 1) * NB * C + ((size_t)slot * NB + chain) * C + cc;
      ull v = aLoad64(rp);
      while ((unsigned)v != expv) v = aLoad64(rp);
      past[lp][cc] = unpackF(v);
    }
  };
  auto gatePrefetch = [&](int l, int buf) {
#pragma unroll
    for (int i = 0; i < 8; ++i) {
      int ci = kg + 16 * i;
      gwf[buf][i] = *(const float2*)(Wf + ((size_t)(l * C + ci) * C + (w * 16 + col)) * 2);
      gwg[buf][i] = *(const float2*)(Wg + ((size_t)(l * C + ci) * C + (w * 16 + col)) * 2);
    }
#pragma unroll
    for (int j = 0; j < 16; ++j)
      wskipr[buf][j] = Wskip[(size_t)(l * C + w * 16 + j) * CS + tid];
    if (l < NL - 1 && tid < C) {
#pragma unroll
      for (int j = 0; j < 16; ++j)
        wresr[buf][j] = Wres[(size_t)(l * C + w * 16 + j) * C + tid];
    }
  };
  auto pastDot = [&](int l, int buf) {
    float a = 0.f, bacc = 0.f;
#pragma unroll
    for (int i = 0; i < 8; ++i) {
      float pv = past[l][kg + 16 * i];
      a += pv * gwf[buf][i].x;
      bacc += pv * gwg[buf][i].x;
    }
    pfp[buf] = a;
    pgp[buf] = bacc;
  };

  // ---- preamble: step-0 rings, layer-0 weights, layer-0 past-dot ----
  ringLoad(0);
  gatePrefetch(0, 0);
  __syncthreads();
  pastDot(0, 0);

  for (int s = 0; s < nsteps - 1; ++s) {
    const unsigned tg = (unsigned)(s + 1);
    float xreg = 0.f;
    if (tid < C) {
      xreg = E[(size_t)tok * C + tid];
      xx[tid] = xreg;
    }
    float skip_acc = 0.f;
    __syncthreads();

#pragma unroll
    for (int l = 0; l < NL; ++l) {
      const int buf = l & 1, nbuf = buf ^ 1;
      // gate: past part (precomputed) + x part
      float pf = pfp[buf], pg = pgp[buf];
#pragma unroll
      for (int i = 0; i < 8; ++i) {
        float xv = xx[kg + 16 * i];
        pf += xv * gwf[buf][i].y;
        pg += xv * gwg[buf][i].y;
      }
      fred[col][kg] = pf;
      gred[col][kg] = pg;
      __syncthreads();
      if (tid < 16) {
        float sf = 0.f, sg = 0.f;
#pragma unroll
        for (int k = 0; k < 16; ++k) { sf += fred[tid][k]; sg += gred[tid][k]; }
        sf += bfl[l][tid];
        sg += bgl[l][tid];
        zbuf[tid] = tanhf(sf) / (1.f + expf(-sg));
      }
      __syncthreads();
      float oldx = xreg;
      if (l < NL - 1) {
        if (tid < C) {
          float part = 0.f;
#pragma unroll
          for (int j = 0; j < 16; ++j) part += zbuf[j] * wresr[buf][j];
          aStore64(&xp[((size_t)l * 8 + w) * C + tid], packF(part, tg));
        }
        // overlap: prefetch next layer, skip acc, next past-dot
        gatePrefetch(l + 1, nbuf);
        {
          float sa = 0.f;
#pragma unroll
          for (int j = 0; j < 16; ++j) sa += zbuf[j] * wskipr[buf][j];
          skip_acc += sa;
        }
        pastDot(l + 1, nbuf);
        // poll partials, update x, write ring[l]
        if (tid < C) {
          const ull* base = &xp[(size_t)l * 8 * C + tid];
          ull v[8];
          bool ok;
          do {
            ok = true;
#pragma unroll
            for (int i2 = 0; i2 < 8; ++i2) v[i2] = aLoad64(base + (size_t)i2 * C);
#pragma unroll
            for (int i2 = 0; i2 < 8; ++i2) ok &= ((unsigned)v[i2] == tg);
          } while (!ok);
          float xnew = oldx + brl[l][tid];
#pragma unroll
          for (int i2 = 0; i2 < 8; ++i2) xnew += unpackF(v[i2]);
          xreg = xnew;
          xx[tid] = xnew;
          if (w == (l & 7)) {
            int D = 1 << l, slot = s & (D - 1);
            aStore64(&rings[(size_t)(D - 1) * NB * C + ((size_t)slot * NB + chain) * C + tid],
                     packF(oldx, tg));
          }
        }
        __syncthreads();
      } else {
        // layer 9: skip acc only; ring write (safe after layer-8 poll)
        {
          float sa = 0.f;
#pragma unroll
          for (int j = 0; j < 16; ++j) sa += zbuf[j] * wskipr[buf][j];
          skip_acc += sa;
        }
        if (w == (9 & 7) && tid < C) {
          int slot = s & 511;
          aStore64(&rings[(size_t)511 * NB * C + ((size_t)slot * NB + chain) * C + tid],
                   packF(xreg, tg));
        }
      }
    }

    // ---- head ----
    aStore64(&skp[(size_t)w * CS + tid], packF(skip_acc, tg));
    // overlap: next-step layer-0 weights, Wo1 slice, next-step rings
    gatePrefetch(0, 0);
    float wo1r[32];
#pragma unroll
    for (int k2 = 0; k2 < 32; ++k2)
      wo1r[k2] = Wo1[(size_t)(hkg * 32 + k2) * CS + w * 32 + hj];
    ringLoad(s + 1);
    // poll skip partials
    {
      const ull* base = &skp[tid];
      ull v[8];
      bool ok;
      do {
        ok = true;
#pragma unroll
        for (int i2 = 0; i2 < 8; ++i2) v[i2] = aLoad64(base + (size_t)i2 * CS);
#pragma unroll
        for (int i2 = 0; i2 < 8; ++i2) ok &= ((unsigned)v[i2] == tg);
      } while (!ok);
      float sk = bsum[tid];
#pragma unroll
      for (int i2 = 0; i2 < 8; ++i2) sk += unpackF(v[i2]);
      skipr[tid] = fmaxf(sk, 0.f);
    }
    __syncthreads();  // covers past[] + skipr
    pastDot(0, 0);    // next step's layer-0 past part
    // h1 partial for cols [32w, 32w+32)
    {
      float a = 0.f;
#pragma unroll
      for (int k2 = 0; k2 < 32; ++k2) a += skipr[hkg * 32 + k2] * wo1r[k2];
      hred[hj][hkg] = a;
    }
    __syncthreads();
    if (tid < 32) {
      float v2 = 0.f;
#pragma unroll
      for (int k2 = 0; k2 < 8; ++k2) v2 += hred[tid][k2];
      v2 += bo1[w * 32 + tid];
      aStore64(&h1p[(size_t)w * 32 + tid], packF(fmaxf(v2, 0.f), tg));
    }
    float wo2r[32];
#pragma unroll
    for (int k2 = 0; k2 < 32; ++k2)
      wo2r[k2] = Wo2[(size_t)(hkg * 32 + k2) * NV + w * 32 + hj];
    // poll h1 (each thread owns one element)
    {
      ull v2 = aLoad64(&h1p[tid]);
      while ((unsigned)v2 != tg) v2 = aLoad64(&h1p[tid]);
      h1f[tid] = unpackF(v2);
    }
    __syncthreads();
    // logits partial
    {
      float a = 0.f;
#pragma unroll
      for (int k2 = 0; k2 < 32; ++k2) a += h1f[hkg * 32 + k2] * wo2r[k2];
      hred[hj][hkg] = a;
    }
    __syncthreads();
    if (tid < 32) {
      float v2 = 0.f;
#pragma unroll
      for (int k2 = 0; k2 < 8; ++k2) v2 += hred[tid][k2];
      lgt[tid] = v2 + bo2[w * 32 + tid];
    }
    __syncthreads();
    if (tid == 0) {
      float bv = lgt[0];
      int bi = 0;
#pragma unroll
      for (int j = 1; j < 32; ++j)
        if (lgt[j] > bv) { bv = lgt[j]; bi = j; }
      ull pv = ((ull)__float_as_uint(bv) << 32) | ((ull)tg << 8) | (unsigned)(w * 32 + bi);
      aStore64(&amx[w], pv);
    }
    if (tid < 8) {
      ull v2 = aLoad64(&amx[tid]);
      while ((unsigned)((v2 >> 8) & 0xFFFFFF) != tg) v2 = aLoad64(&amx[tid]);
      am[tid] = v2;
    }
    __syncthreads();
    {
      float bv = unpackF(am[0]);
      unsigned bi = (unsigned)(am[0] & 255);
#pragma unroll
      for (int i2 = 1; i2 < 8; ++i2) {
        float v2 = unpackF(am[i2]);
        if (v2 > bv) { bv = v2; bi = (unsigned)(am[i2] & 255); }
      }
      tok = bi;
      if (w == 0 && tid == 0) dout[(size_t)chain * ostride + TT + s + 1] = (int)bi;
    }
    __syncthreads();
  }
}

// ---------------- host launcher ---------------------------------------------------
extern "C" void kernel_launch(void* const* d_in, const int* in_sizes, int n_in,
                              void* d_out, int out_size, void* d_ws, size_t ws_size,
                              hipStream_t stream) {
  const int* prompt = (const int*)d_in[0];
  const float* E    = (const float*)d_in[2];
  const float* Wf   = (const float*)d_in[3];
  const float* Wg   = (const float*)d_in[4];
  const float* bf   = (const float*)d_in[5];
  const float* bg   = (const float*)d_in[6];
  const float* Wres = (const float*)d_in[7];
  const float* bres = (const float*)d_in[8];
  const float* Wskip= (const float*)d_in[9];
  const float* bskip= (const float*)d_in[10];
  const float* Wo1  = (const float*)d_in[11];
  const float* bo1  = (const float*)d_in[12];
  const float* Wo2  = (const float*)d_in[13];
  const float* bo2  = (const float*)d_in[14];
  int* dout = (int*)d_out;
  int ostride = out_size / NB;

  char* ws = (char*)d_ws;
  float* X0   = (float*)ws;                    // 16,777,216 B
  float* X1   = (float*)(ws + 16777216);       // 16,777,216 B
  ull* rings  = (ull*)(ws + 33554432);         // 33,521,664 B (sum(d)*32*128 u64)
  float* zlast= (float*)(ws + 67076096);       // 163,840 B
  char* chst  = ws + 67239936;                 // 4,194,304 B

  k_embed<<<1024, 256, 0, stream>>>(prompt, E, X0);
  float* xa = X0;
  float* xb = X1;
  for (int l = 0; l < NL; ++l) {
    k_layer<<<256, 256, 0, stream>>>(xa, xb, Wf, Wg, bf, bg, Wres, bres, rings, zlast, l);
    float* t = xa; xa = xb; xb = t;
  }
  k_head0<<<NB, 256, 0, stream>>>(zlast, Wskip, bskip, Wo1, bo1, Wo2, bo2, chst, dout, ostride);
  k_copyprompt<<<128, 256, 0, stream>>>(prompt, dout, ostride);
  k_decode<<<NB * WPC, NTHR, 0, stream>>>(E, Wf, Wg, bf, bg, Wres, bres, Wskip, bskip,
                                          Wo1, bo1, Wo2, bo2, rings, chst, dout, ostride);
}

// Round 3
// 70483.264 us; speedup vs baseline: 1.2591x; 1.2591x over previous
//
#include <hip/hip_runtime.h>
#include <math.h>

#define NL 10
#define C 128
#define CS 256
#define NV 256
#define NB 32
#define TT 1024
#define WPC 8
#define NTHR 256
#define CH_BYTES 131072  // bytes of exchange state per chain

typedef unsigned long long ull;

// ---------------- atomic helpers (agent scope, relaxed) ---------------------------
__device__ __forceinline__ ull aLoad64(const ull* p) {
  return __hip_atomic_load(p, __ATOMIC_RELAXED, __HIP_MEMORY_SCOPE_AGENT);
}
__device__ __forceinline__ void aStore64(ull* p, ull v) {
  __hip_atomic_store(p, v, __ATOMIC_RELAXED, __HIP_MEMORY_SCOPE_AGENT);
}
__device__ __forceinline__ ull packF(float x, unsigned tag) {
  return ((ull)__float_as_uint(x) << 32) | (ull)tag;
}
__device__ __forceinline__ float unpackF(ull v) {
  return __uint_as_float((unsigned)(v >> 32));
}

// ---------------- K1: embedding lookup ------------------------------------------
__global__ __launch_bounds__(256) void k_embed(const int* __restrict__ prompt,
                                               const float* __restrict__ E,
                                               float* __restrict__ X) {
  int idx = blockIdx.x * 256 + threadIdx.x;
  const float4* E4 = (const float4*)E;
  float4* X4 = (float4*)X;
#pragma unroll
  for (int p = 0; p < 4; ++p) {
    int i = idx + p * 262144;
    int row = i >> 5, c4 = i & 31;
    int tk = prompt[row];
    X4[i] = E4[tk * 32 + c4];
  }
}

// ---------------- K2: one dilated residual layer over full prompt ----------------
__global__ __launch_bounds__(256) void k_layer(
    const float* __restrict__ Xin, float* __restrict__ Xout,
    const float* __restrict__ Wf, const float* __restrict__ Wg,
    const float* __restrict__ bf, const float* __restrict__ bg,
    const float* __restrict__ Wres, const float* __restrict__ bres,
    ull* __restrict__ rings, float* __restrict__ zlast, int l) {
  const int tid = threadIdx.x;
  const int m = blockIdx.x;
  const int b = m >> 3;
  const int t0 = (m & 7) << 7;
  const int d = 1 << l;

  __shared__ __align__(16) float sm[12416];
  float* Axd = sm;                // [16][132]
  float* Ax  = sm + 16 * 132;
  float* Wfs = sm + 32 * 132;     // [16][256]
  float* Wgs = Wfs + 16 * 256;

  const int rg = tid >> 4, cg = tid & 15;

  float af[8][8] = {};
  float ag[8][8] = {};

  for (int kc = 0; kc < 8; ++kc) {
    __syncthreads();
#pragma unroll
    for (int p = 0; p < 2; ++p) {
      int li = tid + p * 256;
      int row = li >> 2, c4 = li & 3;
      int ci = kc * 16 + c4 * 4;
      int t = t0 + row;
      float4 vx = *(const float4*)(Xin + ((size_t)b * TT + t) * C + ci);
      float4 vd = make_float4(0.f, 0.f, 0.f, 0.f);
      int ts = t - d;
      if (ts >= 0) vd = *(const float4*)(Xin + ((size_t)b * TT + ts) * C + ci);
      Ax[(c4 * 4 + 0) * 132 + row] = vx.x;
      Ax[(c4 * 4 + 1) * 132 + row] = vx.y;
      Ax[(c4 * 4 + 2) * 132 + row] = vx.z;
      Ax[(c4 * 4 + 3) * 132 + row] = vx.w;
      Axd[(c4 * 4 + 0) * 132 + row] = vd.x;
      Axd[(c4 * 4 + 1) * 132 + row] = vd.y;
      Axd[(c4 * 4 + 2) * 132 + row] = vd.z;
      Axd[(c4 * 4 + 3) * 132 + row] = vd.w;
    }
#pragma unroll
    for (int p = 0; p < 4; ++p) {
      int li = tid + p * 256;
      int ci = li >> 6, cc = (li & 63) << 2;
      size_t off = ((size_t)(l * C + kc * 16 + ci) * C) * 2 + cc;
      *(float4*)&Wfs[ci * 256 + cc] = *(const float4*)(Wf + off);
      *(float4*)&Wgs[ci * 256 + cc] = *(const float4*)(Wg + off);
    }
    __syncthreads();
    for (int ci = 0; ci < 16; ++ci) {
      float4 d0 = *(float4*)&Axd[ci * 132 + rg * 8];
      float4 d1 = *(float4*)&Axd[ci * 132 + rg * 8 + 4];
      float4 x0 = *(float4*)&Ax[ci * 132 + rg * 8];
      float4 x1 = *(float4*)&Ax[ci * 132 + rg * 8 + 4];
      float axd[8] = {d0.x, d0.y, d0.z, d0.w, d1.x, d1.y, d1.z, d1.w};
      float ax[8]  = {x0.x, x0.y, x0.z, x0.w, x1.x, x1.y, x1.z, x1.w};
#pragma unroll
      for (int jj = 0; jj < 4; ++jj) {
        float4 wf = *(float4*)&Wfs[ci * 256 + cg * 16 + jj * 4];
        float4 wg = *(float4*)&Wgs[ci * 256 + cg * 16 + jj * 4];
#pragma unroll
        for (int i = 0; i < 8; ++i) {
          af[i][2 * jj]     += axd[i] * wf.x + ax[i] * wf.y;
          af[i][2 * jj + 1] += axd[i] * wf.z + ax[i] * wf.w;
          ag[i][2 * jj]     += axd[i] * wg.x + ax[i] * wg.y;
          ag[i][2 * jj + 1] += axd[i] * wg.z + ax[i] * wg.w;
        }
      }
    }
  }

  float bfv[8], bgv[8];
#pragma unroll
  for (int j = 0; j < 8; ++j) {
    bfv[j] = bf[l * C + cg * 8 + j];
    bgv[j] = bg[l * C + cg * 8 + j];
  }
#pragma unroll
  for (int i = 0; i < 8; ++i)
#pragma unroll
    for (int j = 0; j < 8; ++j) {
      float fv = tanhf(af[i][j] + bfv[j]);
      float gv = 1.f / (1.f + expf(-(ag[i][j] + bgv[j])));
      af[i][j] = fv * gv;
    }
  if (((m & 7) == 7) && rg == 15) {
#pragma unroll
    for (int j = 0; j < 8; ++j)
      zlast[((size_t)l * NB + b) * C + cg * 8 + j] = af[7][j];
  }
#pragma unroll
  for (int i = 0; i < 8; ++i)
#pragma unroll
    for (int j = 0; j < 8; ++j) ag[i][j] = 0.f;

  float* zs  = sm;
  float* Wrs = sm + 32 * 132;
  for (int c = 0; c < 4; ++c) {
    __syncthreads();
    if ((cg >> 2) == c) {
      int kl = (cg & 3) * 8;
#pragma unroll
      for (int i = 0; i < 8; ++i)
#pragma unroll
        for (int j = 0; j < 8; ++j) zs[(kl + j) * 132 + rg * 8 + i] = af[i][j];
    }
#pragma unroll
    for (int p = 0; p < 4; ++p) {
      int li = tid + p * 256;
      int kr = li >> 5, cc = (li & 31) << 2;
      *(float4*)&Wrs[kr * 128 + cc] =
          *(const float4*)(Wres + ((size_t)(l * C + c * 32 + kr)) * C + cc);
    }
    __syncthreads();
    for (int k = 0; k < 32; ++k) {
      float4 a0 = *(float4*)&zs[k * 132 + rg * 8];
      float4 a1 = *(float4*)&zs[k * 132 + rg * 8 + 4];
      float4 w0 = *(float4*)&Wrs[k * 128 + cg * 8];
      float4 w1 = *(float4*)&Wrs[k * 128 + cg * 8 + 4];
      float a[8] = {a0.x, a0.y, a0.z, a0.w, a1.x, a1.y, a1.z, a1.w};
      float wv[8] = {w0.x, w0.y, w0.z, w0.w, w1.x, w1.y, w1.z, w1.w};
#pragma unroll
      for (int i = 0; i < 8; ++i)
#pragma unroll
        for (int j = 0; j < 8; ++j) ag[i][j] += a[i] * wv[j];
    }
  }

  float brv[8];
#pragma unroll
  for (int j = 0; j < 8; ++j) brv[j] = bres[l * C + cg * 8 + j];
#pragma unroll
  for (int i = 0; i < 8; ++i) {
    int t = t0 + rg * 8 + i;
    const float4* xi = (const float4*)(Xin + ((size_t)b * TT + t) * C + cg * 8);
    float4 v0 = xi[0], v1 = xi[1];
    float o[8] = {v0.x, v0.y, v0.z, v0.w, v1.x, v1.y, v1.z, v1.w};
#pragma unroll
    for (int j = 0; j < 8; ++j) o[j] += brv[j] + ag[i][j];
    float4* xo = (float4*)(Xout + ((size_t)b * TT + t) * C + cg * 8);
    xo[0] = make_float4(o[0], o[1], o[2], o[3]);
    xo[1] = make_float4(o[4], o[5], o[6], o[7]);
    if (t >= TT - d) {
      int slot = t - (TT - d);
      ull* rp = rings + (size_t)(d - 1) * NB * C + ((size_t)slot * NB + b) * C + cg * 8;
      float vin[8] = {v0.x, v0.y, v0.z, v0.w, v1.x, v1.y, v1.z, v1.w};
#pragma unroll
      for (int j = 0; j < 8; ++j) rp[j] = packF(vin[j], 0u);  // prompt tag = 0
    }
  }
}

// ---------------- K3: skips@T-1 + head -> tok0 -----------------------------------
__global__ __launch_bounds__(256) void k_head0(
    const float* __restrict__ zlast, const float* __restrict__ Wskip,
    const float* __restrict__ bskip, const float* __restrict__ Wo1,
    const float* __restrict__ bo1, const float* __restrict__ Wo2,
    const float* __restrict__ bo2, char* __restrict__ chst,
    int* __restrict__ dout, int ostride) {
  int b = blockIdx.x, tid = threadIdx.x;
  __shared__ float zl[NL][C];
  __shared__ float sr[CS];
  __shared__ float h1[CS];
  __shared__ float lg[NV];
#pragma unroll
  for (int p = 0; p < 5; ++p) {
    int li = tid + p * 256;
    zl[li >> 7][li & 127] = zlast[((size_t)(li >> 7) * NB + b) * C + (li & 127)];
  }
  __syncthreads();
  float s = 0.f;
  for (int l = 0; l < NL; ++l) {
    s += bskip[l * CS + tid];
    const float* wp = Wskip + (size_t)(l * C) * CS + tid;
    for (int k = 0; k < C; ++k) s += zl[l][k] * wp[(size_t)k * CS];
  }
  sr[tid] = fmaxf(s, 0.f);
  __syncthreads();
  float h = bo1[tid];
  {
    const float* wp = Wo1 + tid;
    for (int k = 0; k < CS; ++k) h += sr[k] * wp[(size_t)k * CS];
  }
  h1[tid] = fmaxf(h, 0.f);
  __syncthreads();
  float lv = bo2[tid];
  {
    const float* wp = Wo2 + tid;
    for (int k = 0; k < CS; ++k) lv += h1[k] * wp[(size_t)k * NV];
  }
  lg[tid] = lv;
  __syncthreads();
  if (tid == 0) {
    float bv = lg[0]; int bi = 0;
    for (int v = 1; v < NV; ++v)
      if (lg[v] > bv) { bv = lg[v]; bi = v; }
    *(unsigned*)(chst + (size_t)b * CH_BYTES) = (unsigned)bi;  // tok0
    dout[(size_t)b * ostride + TT] = bi;
  }
}

// ---------------- K4: copy prompt into output ------------------------------------
__global__ __launch_bounds__(256) void k_copyprompt(const int* __restrict__ prompt,
                                                    int* __restrict__ dout,
                                                    int ostride) {
  int idx = blockIdx.x * 256 + threadIdx.x;
  int b = idx >> 10, t = idx & 1023;
  dout[(size_t)b * ostride + t] = prompt[idx];
}

// ---------------- K5: persistent decode (self-tagged dataflow) --------------------
// 32 chains x 8 WGs. w = blockIdx&7 -> XCD id (round-robin heuristic): all WGs on
// one XCD share the SAME weight slice -> per-XCD working set ~750KB, L2-resident.
// WG w owns gate channels [16w,16w+16) and head cols [32w,32w+32).
// All cross-WG data is (float<<32 | step_tag) u64, poll-until-exact-tag (1 RT).
__global__ __launch_bounds__(NTHR, 1) void k_decode(
    const float* __restrict__ E, const float* __restrict__ Wf,
    const float* __restrict__ Wg, const float* __restrict__ bf,
    const float* __restrict__ bg, const float* __restrict__ Wres,
    const float* __restrict__ bres, const float* __restrict__ Wskip,
    const float* __restrict__ bskip, const float* __restrict__ Wo1,
    const float* __restrict__ bo1, const float* __restrict__ Wo2,
    const float* __restrict__ bo2, ull* __restrict__ rings,
    char* __restrict__ chst, int* __restrict__ dout, int ostride) {
  const int tid = threadIdx.x;
  const int w = blockIdx.x & 7;        // == XCD id under round-robin dispatch
  const int chain = blockIdx.x >> 3;
  const int nsteps = ostride - TT;

  char* cb = chst + (size_t)chain * CH_BYTES;
  ull* xp  = (ull*)(cb + 1024);    // [9][8][128]
  ull* skp = (ull*)(cb + 74752);   // [8][256]
  ull* h1p = (ull*)(cb + 91136);   // [256] (w-major slices of 32)
  ull* amx = (ull*)(cb + 93184);   // [8]

  __shared__ float past[NL][C];
  __shared__ float xx[C];
  __shared__ float fred[16][17];
  __shared__ float gred[16][17];
  __shared__ float zbuf[16];
  __shared__ float skipr[CS];
  __shared__ float h1f[CS];
  __shared__ float hred[32][9];
  __shared__ float lgt[32];
  __shared__ ull am[8];
  __shared__ float bfl[NL][16], bgl[NL][16];
  __shared__ float brl[NL - 1][C];
  __shared__ float bsum[CS];

  // ---- bias preloads ----
  for (int li = tid; li < NL * 16; li += NTHR) {
    bfl[li >> 4][li & 15] = bf[(li >> 4) * C + w * 16 + (li & 15)];
    bgl[li >> 4][li & 15] = bg[(li >> 4) * C + w * 16 + (li & 15)];
  }
  for (int li = tid; li < (NL - 1) * C; li += NTHR)
    brl[li >> 7][li & 127] = bres[(li >> 7) * C + (li & 127)];
  {
    float sacc = 0.f;
    for (int l = 0; l < NL; ++l) sacc += bskip[l * CS + tid];
    bsum[tid] = sacc;
  }

  unsigned tok = *(const unsigned*)cb;  // tok0 from k_head0

  const int col = tid & 15, kg = tid >> 4;
  const int hj = tid & 31, hkg = tid >> 5;

  // double-buffered per-layer weight registers (all indices static under unroll)
  float2 gwf[2][8], gwg[2][8];
  float wresr[2][16], wskipr[2][16];

  auto ringLoad = [&](int s2) {
#pragma unroll
    for (int p = 0; p < 5; ++p) {
      int li = tid + p * NTHR;
      int lp = li >> 7, cc = li & 127;
      int D = 1 << lp;
      int slot = s2 & (D - 1);
      unsigned expv = (s2 >= D) ? (unsigned)(s2 - D + 1) : 0u;
      const ull* rp =
          rings + (size_t)(D - 1) * NB * C + ((size_t)slot * NB + chain) * C + cc;
      ull v = aLoad64(rp);
      while ((unsigned)v != expv) v = aLoad64(rp);
      past[lp][cc] = unpackF(v);
    }
  };
  auto gatePrefetch = [&](int l, int buf) {
#pragma unroll
    for (int i = 0; i < 8; ++i) {
      int ci = kg + 16 * i;
      gwf[buf][i] = *(const float2*)(Wf + ((size_t)(l * C + ci) * C + (w * 16 + col)) * 2);
      gwg[buf][i] = *(const float2*)(Wg + ((size_t)(l * C + ci) * C + (w * 16 + col)) * 2);
    }
#pragma unroll
    for (int j = 0; j < 16; ++j)
      wskipr[buf][j] = Wskip[(size_t)(l * C + w * 16 + j) * CS + tid];
    if (l < NL - 1 && tid < C) {
#pragma unroll
      for (int j = 0; j < 16; ++j)
        wresr[buf][j] = Wres[(size_t)(l * C + w * 16 + j) * C + tid];
    }
  };

  // ---- preamble: step-0 rings, layer-0 weights ----
  ringLoad(0);
  gatePrefetch(0, 0);
  __syncthreads();

  for (int s = 0; s < nsteps - 1; ++s) {
    const unsigned tg = (unsigned)(s + 1);
    float xreg = 0.f;
    if (tid < C) {
      xreg = E[(size_t)tok * C + tid];
      xx[tid] = xreg;
    }
    float skip_acc = 0.f;
    __syncthreads();

#pragma unroll
    for (int l = 0; l < NL; ++l) {
      const int buf = l & 1, nbuf = buf ^ 1;
      // gate dot: past + x fused, weights already in regs (L2-hit prefetched)
      float pf = 0.f, pg = 0.f;
#pragma unroll
      for (int i = 0; i < 8; ++i) {
        int ci = kg + 16 * i;
        float pv = past[l][ci], xv = xx[ci];
        pf += pv * gwf[buf][i].x + xv * gwf[buf][i].y;
        pg += pv * gwg[buf][i].x + xv * gwg[buf][i].y;
      }
      fred[col][kg] = pf;
      gred[col][kg] = pg;
      __syncthreads();
      if (tid < 16) {
        float sf = 0.f, sg = 0.f;
#pragma unroll
        for (int k = 0; k < 16; ++k) { sf += fred[tid][k]; sg += gred[tid][k]; }
        sf += bfl[l][tid];
        sg += bgl[l][tid];
        zbuf[tid] = tanhf(sf) / (1.f + expf(-sg));
      }
      __syncthreads();
      float oldx = xreg;
      if (l < NL - 1) {
        // 1) partial-x store (critical for other WGs) + ring write (pre-update x)
        if (tid < C) {
          float part = 0.f;
#pragma unroll
          for (int j = 0; j < 16; ++j) part += zbuf[j] * wresr[buf][j];
          aStore64(&xp[((size_t)l * 8 + w) * C + tid], packF(part, tg));
          if (w == (l & 7)) {
            int D = 1 << l, slot = s & (D - 1);
            aStore64(&rings[(size_t)(D - 1) * NB * C + ((size_t)slot * NB + chain) * C + tid],
                     packF(oldx, tg));
          }
        }
        // 2) overlap: next-layer weights (L2-resident now), skip accumulation
        gatePrefetch(l + 1, nbuf);
        {
          float sa = 0.f;
#pragma unroll
          for (int j = 0; j < 16; ++j) sa += zbuf[j] * wskipr[buf][j];
          skip_acc += sa;
        }
        // 3) poll partials, update x
        if (tid < C) {
          const ull* base = &xp[(size_t)l * 8 * C + tid];
          ull v[8];
          bool ok;
          do {
            ok = true;
#pragma unroll
            for (int i2 = 0; i2 < 8; ++i2) v[i2] = aLoad64(base + (size_t)i2 * C);
#pragma unroll
            for (int i2 = 0; i2 < 8; ++i2) ok &= ((unsigned)v[i2] == tg);
          } while (!ok);
          float xnew = oldx + brl[l][tid];
#pragma unroll
          for (int i2 = 0; i2 < 8; ++i2) xnew += unpackF(v[i2]);
          xreg = xnew;
          xx[tid] = xnew;
        }
        __syncthreads();
      } else {
        // layer 9: skip acc only; ring write (x unchanged)
        {
          float sa = 0.f;
#pragma unroll
          for (int j = 0; j < 16; ++j) sa += zbuf[j] * wskipr[buf][j];
          skip_acc += sa;
        }
        if (w == (9 & 7) && tid < C) {
          int slot = s & 511;
          aStore64(&rings[(size_t)511 * NB * C + ((size_t)slot * NB + chain) * C + tid],
                   packF(xreg, tg));
        }
      }
    }

    // ---- head ----
    aStore64(&skp[(size_t)w * CS + tid], packF(skip_acc, tg));
    // overlap: next-step layer-0 weights, Wo1 slice, next-step rings
    gatePrefetch(0, 0);
    float wo1r[32];
#pragma unroll
    for (int k2 = 0; k2 < 32; ++k2)
      wo1r[k2] = Wo1[(size_t)(hkg * 32 + k2) * CS + w * 32 + hj];
    ringLoad(s + 1);
    // poll skip partials
    {
      const ull* base = &skp[tid];
      ull v[8];
      bool ok;
      do {
        ok = true;
#pragma unroll
        for (int i2 = 0; i2 < 8; ++i2) v[i2] = aLoad64(base + (size_t)i2 * CS);
#pragma unroll
        for (int i2 = 0; i2 < 8; ++i2) ok &= ((unsigned)v[i2] == tg);
      } while (!ok);
      float sk = bsum[tid];
#pragma unroll
      for (int i2 = 0; i2 < 8; ++i2) sk += unpackF(v[i2]);
      skipr[tid] = fmaxf(sk, 0.f);
    }
    __syncthreads();
    // h1 partial for cols [32w, 32w+32)
    {
      float a = 0.f;
#pragma unroll
      for (int k2 = 0; k2 < 32; ++k2) a += skipr[hkg * 32 + k2] * wo1r[k2];
      hred[hj][hkg] = a;
    }
    __syncthreads();
    if (tid < 32) {
      float v2 = 0.f;
#pragma unroll
      for (int k2 = 0; k2 < 8; ++k2) v2 += hred[tid][k2];
      v2 += bo1[w * 32 + tid];
      aStore64(&h1p[(size_t)w * 32 + tid], packF(fmaxf(v2, 0.f), tg));
    }
    float wo2r[32];
#pragma unroll
    for (int k2 = 0; k2 < 32; ++k2)
      wo2r[k2] = Wo2[(size_t)(hkg * 32 + k2) * NV + w * 32 + hj];
    // poll h1 (each thread owns one element)
    {
      ull v2 = aLoad64(&h1p[tid]);
      while ((unsigned)v2 != tg) v2 = aLoad64(&h1p[tid]);
      h1f[tid] = unpackF(v2);
    }
    __syncthreads();
    // logits partial
    {
      float a = 0.f;
#pragma unroll
      for (int k2 = 0; k2 < 32; ++k2) a += h1f[hkg * 32 + k2] * wo2r[k2];
      hred[hj][hkg] = a;
    }
    __syncthreads();
    if (tid < 32) {
      float v2 = 0.f;
#pragma unroll
      for (int k2 = 0; k2 < 8; ++k2) v2 += hred[tid][k2];
      lgt[tid] = v2 + bo2[w * 32 + tid];
    }
    __syncthreads();
    if (tid == 0) {
      float bv = lgt[0];
      int bi = 0;
#pragma unroll
      for (int j = 1; j < 32; ++j)
        if (lgt[j] > bv) { bv = lgt[j]; bi = j; }
      ull pv = ((ull)__float_as_uint(bv) << 32) | ((ull)tg << 8) | (unsigned)(w * 32 + bi);
      aStore64(&amx[w], pv);
    }
    if (tid < 8) {
      ull v2 = aLoad64(&amx[tid]);
      while ((unsigned)((v2 >> 8) & 0xFFFFFF) != tg) v2 = aLoad64(&amx[tid]);
      am[tid] = v2;
    }
    __syncthreads();
    {
      float bv = unpackF(am[0]);
      unsigned bi = (unsigned)(am[0] & 255);
#pragma unroll
      for (int i2 = 1; i2 < 8; ++i2) {
        float v2 = unpackF(am[i2]);
        if (v2 > bv) { bv = v2; bi = (unsigned)(am[i2] & 255); }
      }
      tok = bi;
      if (w == 0 && tid == 0) dout[(size_t)chain * ostride + TT + s + 1] = (int)bi;
    }
    __syncthreads();
  }
}

// ---------------- host launcher ---------------------------------------------------
extern "C" void kernel_launch(void* const* d_in, const int* in_sizes, int n_in,
                              void* d_out, int out_size, void* d_ws, size_t ws_size,
                              hipStream_t stream) {
  const int* prompt = (const int*)d_in[0];
  const float* E    = (const float*)d_in[2];
  const float* Wf   = (const float*)d_in[3];
  const float* Wg   = (const float*)d_in[4];
  const float* bf   = (const float*)d_in[5];
  const float* bg   = (const float*)d_in[6];
  const float* Wres = (const float*)d_in[7];
  const float* bres = (const float*)d_in[8];
  const float* Wskip= (const float*)d_in[9];
  const float* bskip= (const float*)d_in[10];
  const float* Wo1  = (const float*)d_in[11];
  const float* bo1  = (const float*)d_in[12];
  const float* Wo2  = (const float*)d_in[13];
  const float* bo2  = (const float*)d_in[14];
  int* dout = (int*)d_out;
  int ostride = out_size / NB;

  char* ws = (char*)d_ws;
  float* X0   = (float*)ws;                    // 16,777,216 B
  float* X1   = (float*)(ws + 16777216);       // 16,777,216 B
  ull* rings  = (ull*)(ws + 33554432);         // 33,521,664 B (sum(d)*32*128 u64)
  float* zlast= (float*)(ws + 67076096);       // 163,840 B
  char* chst  = ws + 67239936;                 // 4,194,304 B

  k_embed<<<1024, 256, 0, stream>>>(prompt, E, X0);
  float* xa = X0;
  float* xb = X1;
  for (int l = 0; l < NL; ++l) {
    k_layer<<<256, 256, 0, stream>>>(xa, xb, Wf, Wg, bf, bg, Wres, bres, rings, zlast, l);
    float* t = xa; xa = xb; xb = t;
  }
  k_head0<<<NB, 256, 0, stream>>>(zlast, Wskip, bskip, Wo1, bo1, Wo2, bo2, chst, dout, ostride);
  k_copyprompt<<<128, 256, 0, stream>>>(prompt, dout, ostride);
  k_decode<<<NB * WPC, NTHR, 0, stream>>>(E, Wf, Wg, bf, bg, Wres, bres, Wskip, bskip,
                                          Wo1, bo1, Wo2, bo2, rings, chst, dout, ostride);
}

// Round 5
// 58198.022 us; speedup vs baseline: 1.5249x; 1.2111x over previous
//
#include <hip/hip_runtime.h>
#include <math.h>

#define NL 10
#define C 128
#define CS 256
#define NV 256
#define NB 32
#define TT 1024
#define NTHR 512
#define CH_BYTES 131072

typedef unsigned long long ull;

__device__ __forceinline__ ull aLoad64(const ull* p) {
  return __hip_atomic_load(p, __ATOMIC_RELAXED, __HIP_MEMORY_SCOPE_AGENT);
}
__device__ __forceinline__ void aStore64(ull* p, ull v) {
  __hip_atomic_store(p, v, __ATOMIC_RELAXED, __HIP_MEMORY_SCOPE_AGENT);
}
__device__ __forceinline__ ull packF(float x, unsigned tag) {
  return ((ull)__float_as_uint(x) << 32) | (ull)tag;
}
__device__ __forceinline__ float unpackF(ull v) {
  return __uint_as_float((unsigned)(v >> 32));
}

// ---------------- K1: embedding lookup ------------------------------------------
__global__ __launch_bounds__(256) void k_embed(const int* __restrict__ prompt,
                                               const float* __restrict__ E,
                                               float* __restrict__ X) {
  int idx = blockIdx.x * 256 + threadIdx.x;
  const float4* E4 = (const float4*)E;
  float4* X4 = (float4*)X;
#pragma unroll
  for (int p = 0; p < 4; ++p) {
    int i = idx + p * 262144;
    int row = i >> 5, c4 = i & 31;
    int tk = prompt[row];
    X4[i] = E4[tk * 32 + c4];
  }
}

// ---------------- K1b: de-interleave Wf/Wg taps (L*C*C = 163840 elems/tap) -------
__global__ __launch_bounds__(256) void k_deint(const float* __restrict__ Wf,
                                               const float* __restrict__ Wg,
                                               float* __restrict__ Wf0c,
                                               float* __restrict__ Wf1c,
                                               float* __restrict__ Wg0c,
                                               float* __restrict__ Wg1c) {
  int i = blockIdx.x * 256 + threadIdx.x;  // < 163840
  float2 f = *(const float2*)(Wf + 2 * (size_t)i);
  float2 g = *(const float2*)(Wg + 2 * (size_t)i);
  Wf0c[i] = f.x; Wf1c[i] = f.y; Wg0c[i] = g.x; Wg1c[i] = g.y;
}

// ---------------- K2: one dilated residual layer over full prompt ----------------
__global__ __launch_bounds__(256) void k_layer(
    const float* __restrict__ Xin, float* __restrict__ Xout,
    const float* __restrict__ Wf, const float* __restrict__ Wg,
    const float* __restrict__ bf, const float* __restrict__ bg,
    const float* __restrict__ Wres, const float* __restrict__ bres,
    ull* __restrict__ rings, float* __restrict__ zlast, int l) {
  const int tid = threadIdx.x;
  const int m = blockIdx.x;
  const int b = m >> 3;
  const int t0 = (m & 7) << 7;
  const int d = 1 << l;

  __shared__ __align__(16) float sm[12416];
  float* Axd = sm;
  float* Ax  = sm + 16 * 132;
  float* Wfs = sm + 32 * 132;
  float* Wgs = Wfs + 16 * 256;

  const int rg = tid >> 4, cg = tid & 15;

  float af[8][8] = {};
  float ag[8][8] = {};

  for (int kc = 0; kc < 8; ++kc) {
    __syncthreads();
#pragma unroll
    for (int p = 0; p < 2; ++p) {
      int li = tid + p * 256;
      int row = li >> 2, c4 = li & 3;
      int ci = kc * 16 + c4 * 4;
      int t = t0 + row;
      float4 vx = *(const float4*)(Xin + ((size_t)b * TT + t) * C + ci);
      float4 vd = make_float4(0.f, 0.f, 0.f, 0.f);
      int ts = t - d;
      if (ts >= 0) vd = *(const float4*)(Xin + ((size_t)b * TT + ts) * C + ci);
      Ax[(c4 * 4 + 0) * 132 + row] = vx.x;
      Ax[(c4 * 4 + 1) * 132 + row] = vx.y;
      Ax[(c4 * 4 + 2) * 132 + row] = vx.z;
      Ax[(c4 * 4 + 3) * 132 + row] = vx.w;
      Axd[(c4 * 4 + 0) * 132 + row] = vd.x;
      Axd[(c4 * 4 + 1) * 132 + row] = vd.y;
      Axd[(c4 * 4 + 2) * 132 + row] = vd.z;
      Axd[(c4 * 4 + 3) * 132 + row] = vd.w;
    }
#pragma unroll
    for (int p = 0; p < 4; ++p) {
      int li = tid + p * 256;
      int ci = li >> 6, cc = (li & 63) << 2;
      size_t off = ((size_t)(l * C + kc * 16 + ci) * C) * 2 + cc;
      *(float4*)&Wfs[ci * 256 + cc] = *(const float4*)(Wf + off);
      *(float4*)&Wgs[ci * 256 + cc] = *(const float4*)(Wg + off);
    }
    __syncthreads();
    for (int ci = 0; ci < 16; ++ci) {
      float4 d0 = *(float4*)&Axd[ci * 132 + rg * 8];
      float4 d1 = *(float4*)&Axd[ci * 132 + rg * 8 + 4];
      float4 x0 = *(float4*)&Ax[ci * 132 + rg * 8];
      float4 x1 = *(float4*)&Ax[ci * 132 + rg * 8 + 4];
      float axd[8] = {d0.x, d0.y, d0.z, d0.w, d1.x, d1.y, d1.z, d1.w};
      float ax[8]  = {x0.x, x0.y, x0.z, x0.w, x1.x, x1.y, x1.z, x1.w};
#pragma unroll
      for (int jj = 0; jj < 4; ++jj) {
        float4 wf = *(float4*)&Wfs[ci * 256 + cg * 16 + jj * 4];
        float4 wg = *(float4*)&Wgs[ci * 256 + cg * 16 + jj * 4];
#pragma unroll
        for (int i = 0; i < 8; ++i) {
          af[i][2 * jj]     += axd[i] * wf.x + ax[i] * wf.y;
          af[i][2 * jj + 1] += axd[i] * wf.z + ax[i] * wf.w;
          ag[i][2 * jj]     += axd[i] * wg.x + ax[i] * wg.y;
          ag[i][2 * jj + 1] += axd[i] * wg.z + ax[i] * wg.w;
        }
      }
    }
  }

  float bfv[8], bgv[8];
#pragma unroll
  for (int j = 0; j < 8; ++j) {
    bfv[j] = bf[l * C + cg * 8 + j];
    bgv[j] = bg[l * C + cg * 8 + j];
  }
#pragma unroll
  for (int i = 0; i < 8; ++i)
#pragma unroll
    for (int j = 0; j < 8; ++j) {
      float fv = tanhf(af[i][j] + bfv[j]);
      float gv = 1.f / (1.f + expf(-(ag[i][j] + bgv[j])));
      af[i][j] = fv * gv;
    }
  if (((m & 7) == 7) && rg == 15) {
#pragma unroll
    for (int j = 0; j < 8; ++j)
      zlast[((size_t)l * NB + b) * C + cg * 8 + j] = af[7][j];
  }
#pragma unroll
  for (int i = 0; i < 8; ++i)
#pragma unroll
    for (int j = 0; j < 8; ++j) ag[i][j] = 0.f;

  float* zs  = sm;
  float* Wrs = sm + 32 * 132;
  for (int c = 0; c < 4; ++c) {
    __syncthreads();
    if ((cg >> 2) == c) {
      int kl = (cg & 3) * 8;
#pragma unroll
      for (int i = 0; i < 8; ++i)
#pragma unroll
        for (int j = 0; j < 8; ++j) zs[(kl + j) * 132 + rg * 8 + i] = af[i][j];
    }
#pragma unroll
    for (int p = 0; p < 4; ++p) {
      int li = tid + p * 256;
      int kr = li >> 5, cc = (li & 31) << 2;
      *(float4*)&Wrs[kr * 128 + cc] =
          *(const float4*)(Wres + ((size_t)(l * C + c * 32 + kr)) * C + cc);
    }
    __syncthreads();
    for (int k = 0; k < 32; ++k) {
      float4 a0 = *(float4*)&zs[k * 132 + rg * 8];
      float4 a1 = *(float4*)&zs[k * 132 + rg * 8 + 4];
      float4 w0 = *(float4*)&Wrs[k * 128 + cg * 8];
      float4 w1 = *(float4*)&Wrs[k * 128 + cg * 8 + 4];
      float a[8] = {a0.x, a0.y, a0.z, a0.w, a1.x, a1.y, a1.z, a1.w};
      float wv[8] = {w0.x, w0.y, w0.z, w0.w, w1.x, w1.y, w1.z, w1.w};
#pragma unroll
      for (int i = 0; i < 8; ++i)
#pragma unroll
        for (int j = 0; j < 8; ++j) ag[i][j] += a[i] * wv[j];
    }
  }

  float brv[8];
#pragma unroll
  for (int j = 0; j < 8; ++j) brv[j] = bres[l * C + cg * 8 + j];
#pragma unroll
  for (int i = 0; i < 8; ++i) {
    int t = t0 + rg * 8 + i;
    const float4* xi = (const float4*)(Xin + ((size_t)b * TT + t) * C + cg * 8);
    float4 v0 = xi[0], v1 = xi[1];
    float o[8] = {v0.x, v0.y, v0.z, v0.w, v1.x, v1.y, v1.z, v1.w};
#pragma unroll
    for (int j = 0; j < 8; ++j) o[j] += brv[j] + ag[i][j];
    float4* xo = (float4*)(Xout + ((size_t)b * TT + t) * C + cg * 8);
    xo[0] = make_float4(o[0], o[1], o[2], o[3]);
    xo[1] = make_float4(o[4], o[5], o[6], o[7]);
    if (t >= TT - d) {
      int slot = t - (TT - d);
      ull* rp = rings + (size_t)(d - 1) * NB * C + ((size_t)slot * NB + b) * C + cg * 8;
      float vin[8] = {v0.x, v0.y, v0.z, v0.w, v1.x, v1.y, v1.z, v1.w};
#pragma unroll
      for (int j = 0; j < 8; ++j) rp[j] = packF(vin[j], 0u);
    }
  }
}

// ---------------- K3: skips@T-1 + head -> tok0 -----------------------------------
__global__ __launch_bounds__(256) void k_head0(
    const float* __restrict__ zlast, const float* __restrict__ Wskip,
    const float* __restrict__ bskip, const float* __restrict__ Wo1,
    const float* __restrict__ bo1, const float* __restrict__ Wo2,
    const float* __restrict__ bo2, char* __restrict__ chst,
    int* __restrict__ dout, int ostride) {
  int b = blockIdx.x, tid = threadIdx.x;
  __shared__ float zl[NL][C];
  __shared__ float sr[CS];
  __shared__ float h1[CS];
  __shared__ float lg[NV];
#pragma unroll
  for (int p = 0; p < 5; ++p) {
    int li = tid + p * 256;
    zl[li >> 7][li & 127] = zlast[((size_t)(li >> 7) * NB + b) * C + (li & 127)];
  }
  __syncthreads();
  float s = 0.f;
  for (int l = 0; l < NL; ++l) {
    s += bskip[l * CS + tid];
    const float* wp = Wskip + (size_t)(l * C) * CS + tid;
    for (int k = 0; k < C; ++k) s += zl[l][k] * wp[(size_t)k * CS];
  }
  sr[tid] = fmaxf(s, 0.f);
  __syncthreads();
  float h = bo1[tid];
  {
    const float* wp = Wo1 + tid;
    for (int k = 0; k < CS; ++k) h += sr[k] * wp[(size_t)k * CS];
  }
  h1[tid] = fmaxf(h, 0.f);
  __syncthreads();
  float lv = bo2[tid];
  {
    const float* wp = Wo2 + tid;
    for (int k = 0; k < CS; ++k) lv += h1[k] * wp[(size_t)k * NV];
  }
  lg[tid] = lv;
  __syncthreads();
  if (tid == 0) {
    float bv = lg[0]; int bi = 0;
    for (int v = 1; v < NV; ++v)
      if (lg[v] > bv) { bv = lg[v]; bi = v; }
    *(unsigned*)(chst + (size_t)b * CH_BYTES) = (unsigned)bi;
    dout[(size_t)b * ostride + TT] = bi;
  }
}

// ---------------- K4: copy prompt into output ------------------------------------
__global__ __launch_bounds__(256) void k_copyprompt(const int* __restrict__ prompt,
                                                    int* __restrict__ dout,
                                                    int ostride) {
  int idx = blockIdx.x * 256 + threadIdx.x;
  int b = idx >> 10, t = idx & 1023;
  dout[(size_t)b * ostride + t] = prompt[idx];
}

// ---------------- K5: persistent decode -------------------------------------------
// Roles by XCD (blockIdx&7): xcd 0-3 = serial (8 chains/XCD, full x-chain + head
// locally; weights L2-resident per XCD). xcd 4-5 = P-helpers (past-tap gate parts,
// parallel ring poll). xcd 6-7 = S-helpers (all 10 skip partials). Exchange =
// tagged u64 (float<<32|step), poll-until-exact-tag; no grid barriers anywhere.
__global__ __launch_bounds__(NTHR) void k_decode(
    const float* __restrict__ E,
    const float* __restrict__ Wf1c, const float* __restrict__ Wg1c,
    const float* __restrict__ Wf0c, const float* __restrict__ Wg0c,
    const float* __restrict__ bf, const float* __restrict__ bg,
    const float* __restrict__ Wres, const float* __restrict__ bres,
    const float* __restrict__ Wskip, const float* __restrict__ bskip,
    const float* __restrict__ Wo1, const float* __restrict__ bo1,
    const float* __restrict__ Wo2, const float* __restrict__ bo2,
    ull* __restrict__ rings, char* __restrict__ chst,
    int* __restrict__ dout, int ostride) {
  const int tid = threadIdx.x;
  const int xcd = blockIdx.x & 7, slot = blockIdx.x >> 3;
  const int nsteps = ostride - TT;

  int role, chain;
  if (xcd < 4)      { if (slot >= 8)  return; role = 0; chain = xcd * 8 + slot; }
  else if (xcd < 6) { if (slot >= 16) return; role = 1; chain = (xcd - 4) * 16 + slot; }
  else              { if (slot >= 16) return; role = 2; chain = (xcd - 6) * 16 + slot; }

  char* cb = chst + (size_t)chain * CH_BYTES;
  ull* P      = (ull*)(cb + 4096);    // [2 par][10 l][2 fg][128]
  ull* zpub   = (ull*)(cb + 49152);   // [10][128]
  ull* skpart = (ull*)(cb + 61440);   // [2 par][256]

  __shared__ __align__(16) float SM[9984];
  __shared__ unsigned tokS;
  float* REDF = SM;              // [16][132]; head reuse as [8][260]
  float* REDG = SM + 2112;       // [16][132]
  float* XX   = SM + 4224;       // [128] (serial)
  float* ZSH  = SM + 4352;       // [128] (serial z / S-helper z)
  float* SK   = SM + 4480;       // [256]
  float* H1F  = SM + 4736;       // [256]
  float* LGT  = SM + 4992;       // [256]
  float* BRES = SM + 5248;       // [9][128]
  float* BSUM = SM + 6400;       // [256]
  float* BO1  = SM + 6656;       // [256]
  float* BO2  = SM + 6912;       // [256]
  float* PASTP= SM + 4224;       // (P role) [10][128] : 4224..5504
  float* BFP  = SM + 5504;       // (P role) [10][128]
  float* BGP  = SM + 6784;       // (P role) [10][128] : ..8064

  // =========================== SERIAL ==========================================
  if (role == 0) {
    for (int li = tid; li < 9 * C; li += NTHR) BRES[li] = bres[li];
    if (tid < CS) {
      float sacc = 0.f;
      for (int l = 0; l < NL; ++l) sacc += bskip[l * CS + tid];
      BSUM[tid] = sacc;
      BO1[tid] = bo1[tid];
      BO2[tid] = bo2[tid];
    }
    unsigned tok = *(const unsigned*)cb;
    __syncthreads();

    const int j4 = tid & 31, ks = tid >> 5;      // 128-out matvecs: 16-way K
    const int j4b = tid & 63, ksb = tid >> 6;    // 256-out matvecs: 8-way K

    for (int s = 0; s < nsteps - 1; ++s) {
      const unsigned tg = (unsigned)(s + 1);
      const int par = s & 1;

      ull pva[20];
      if (tid < C) {
        float xv0 = E[(size_t)tok * C + tid];
#pragma unroll
        for (int l = 0; l < NL; ++l) {
          pva[2 * l]     = aLoad64(&P[((par * 10 + l) * 2 + 0) * 128 + tid]);
          pva[2 * l + 1] = aLoad64(&P[((par * 10 + l) * 2 + 1) * 128 + tid]);
        }
        for (;;) {
          bool ok = true;
#pragma unroll
          for (int i = 0; i < 20; ++i) ok &= ((unsigned)pva[i] == tg);
          if (ok) break;
#pragma unroll
          for (int i = 0; i < 20; ++i)
            if ((unsigned)pva[i] != tg)
              pva[i] = aLoad64(&P[((par * 10 + (i >> 1)) * 2 + (i & 1)) * 128 + tid]);
        }
        XX[tid] = xv0;
      }
      __syncthreads();

#pragma unroll
      for (int l = 0; l < NL; ++l) {
        const float4* wfp = (const float4*)(Wf1c + (size_t)l * C * C) + (8 * ks) * 32 + j4;
        const float4* wgp = (const float4*)(Wg1c + (size_t)l * C * C) + (8 * ks) * 32 + j4;
        const float4* wrp = (const float4*)(Wres + (size_t)l * C * C) + (8 * ks) * 32 + j4;
        float4 aF = make_float4(0, 0, 0, 0), aG = make_float4(0, 0, 0, 0);
        float4 wrv[8];
#pragma unroll
        for (int kk = 0; kk < 8; ++kk) {
          float xv = XX[8 * ks + kk];
          float4 wf = wfp[kk * 32];
          float4 wg = wgp[kk * 32];
          if (l < 9) wrv[kk] = wrp[kk * 32];
          aF.x += xv * wf.x; aF.y += xv * wf.y; aF.z += xv * wf.z; aF.w += xv * wf.w;
          aG.x += xv * wg.x; aG.y += xv * wg.y; aG.z += xv * wg.z; aG.w += xv * wg.w;
        }
        *(float4*)&REDF[ks * 132 + 4 * j4] = aF;
        *(float4*)&REDG[ks * 132 + 4 * j4] = aG;
        __syncthreads();
        if (tid < C) {
          float F = unpackF(pva[2 * l]), G = unpackF(pva[2 * l + 1]);
#pragma unroll
          for (int r = 0; r < 16; ++r) { F += REDF[r * 132 + tid]; G += REDG[r * 132 + tid]; }
          float z = tanhf(F) * (1.f / (1.f + expf(-G)));
          ZSH[tid] = z;
          aStore64(&zpub[l * 128 + tid], packF(z, tg));
          int D = 1 << l, slo = s & (D - 1);
          aStore64(&rings[(size_t)(D - 1) * NB * C + ((size_t)slo * NB + chain) * C + tid],
                   packF(XX[tid], tg));
        }
        __syncthreads();
        if (l < 9) {
          float4 aR = make_float4(0, 0, 0, 0);
#pragma unroll
          for (int kk = 0; kk < 8; ++kk) {
            float zv = ZSH[8 * ks + kk];
            aR.x += zv * wrv[kk].x; aR.y += zv * wrv[kk].y;
            aR.z += zv * wrv[kk].z; aR.w += zv * wrv[kk].w;
          }
          *(float4*)&REDF[ks * 132 + 4 * j4] = aR;
          __syncthreads();
          if (tid < C) {
            float v = BRES[l * C + tid];
#pragma unroll
            for (int r = 0; r < 16; ++r) v += REDF[r * 132 + tid];
            XX[tid] += v;
          }
          __syncthreads();
        }
      }

      // ---- head: skips from S-helper, Wo1/Wo2 local ----
      if (tid < CS) {
        const ull* sp = &skpart[(size_t)par * 256 + tid];
        ull v = aLoad64(sp);
        while ((unsigned)v != tg) v = aLoad64(sp);
        SK[tid] = fmaxf(BSUM[tid] + unpackF(v), 0.f);
      }
      __syncthreads();
      {
        float4 aH = make_float4(0, 0, 0, 0);
#pragma unroll
        for (int kk = 0; kk < 32; ++kk) {
          float sv = SK[32 * ksb + kk];
          float4 w = *((const float4*)Wo1 + (size_t)(32 * ksb + kk) * 64 + j4b);
          aH.x += sv * w.x; aH.y += sv * w.y; aH.z += sv * w.z; aH.w += sv * w.w;
        }
        *(float4*)&REDF[ksb * 260 + 4 * j4b] = aH;
      }
      __syncthreads();
      if (tid < CS) {
        float v = BO1[tid];
#pragma unroll
        for (int r = 0; r < 8; ++r) v += REDF[r * 260 + tid];
        H1F[tid] = fmaxf(v, 0.f);
      }
      __syncthreads();
      {
        float4 aL = make_float4(0, 0, 0, 0);
#pragma unroll
        for (int kk = 0; kk < 32; ++kk) {
          float hv = H1F[32 * ksb + kk];
          float4 w = *((const float4*)Wo2 + (size_t)(32 * ksb + kk) * 64 + j4b);
          aL.x += hv * w.x; aL.y += hv * w.y; aL.z += hv * w.z; aL.w += hv * w.w;
        }
        *(float4*)&REDF[ksb * 260 + 4 * j4b] = aL;
      }
      __syncthreads();
      if (tid < CS) {
        float v = BO2[tid];
#pragma unroll
        for (int r = 0; r < 8; ++r) v += REDF[r * 260 + tid];
        LGT[tid] = v;
      }
      __syncthreads();
      if (tid < 64) {
        float bv = LGT[4 * tid]; int bi = 4 * tid;
#pragma unroll
        for (int q = 1; q < 4; ++q) {
          float vq = LGT[4 * tid + q];
          if (vq > bv) { bv = vq; bi = 4 * tid + q; }
        }
#pragma unroll
        for (int off = 32; off >= 1; off >>= 1) {
          float ov = __shfl_down(bv, off);
          int oi = __shfl_down(bi, off);
          if (ov > bv || (ov == bv && oi < bi)) { bv = ov; bi = oi; }
        }
        if (tid == 0) {
          tokS = (unsigned)bi;
          dout[(size_t)chain * ostride + TT + 1 + s] = bi;
        }
      }
      __syncthreads();
      tok = tokS;
      __syncthreads();
    }
    return;
  }

  // =========================== P-HELPER =======================================
  if (role == 1) {
    for (int li = tid; li < NL * C; li += NTHR) { BFP[li] = bf[li]; BGP[li] = bg[li]; }
    __syncthreads();
    const int j4 = tid & 31, ks = tid >> 5;
    for (int s = 0; s < nsteps - 1; ++s) {
      const unsigned tg = (unsigned)(s + 1);
      const int par = s & 1;
      // parallel poll of all 10 ring rows for this step
      if (tid < C) {
        ull rv[10];
#pragma unroll
        for (int l = 0; l < NL; ++l) {
          int D = 1 << l, slo = s & (D - 1);
          rv[l] = aLoad64(rings + (size_t)(D - 1) * NB * C +
                          ((size_t)slo * NB + chain) * C + tid);
        }
        for (;;) {
          bool ok = true;
#pragma unroll
          for (int l = 0; l < NL; ++l) {
            int D = 1 << l;
            unsigned expv = (s >= D) ? (unsigned)(s - D + 1) : 0u;
            ok &= ((unsigned)rv[l] == expv);
          }
          if (ok) break;
#pragma unroll
          for (int l = 0; l < NL; ++l) {
            int D = 1 << l;
            unsigned expv = (s >= D) ? (unsigned)(s - D + 1) : 0u;
            if ((unsigned)rv[l] != expv) {
              int slo = s & (D - 1);
              rv[l] = aLoad64(rings + (size_t)(D - 1) * NB * C +
                              ((size_t)slo * NB + chain) * C + tid);
            }
          }
        }
#pragma unroll
        for (int l = 0; l < NL; ++l) PASTP[l * 128 + tid] = unpackF(rv[l]);
      }
      __syncthreads();
#pragma unroll
      for (int l = 0; l < NL; ++l) {
        const float4* wfp = (const float4*)(Wf0c + (size_t)l * C * C) + (8 * ks) * 32 + j4;
        const float4* wgp = (const float4*)(Wg0c + (size_t)l * C * C) + (8 * ks) * 32 + j4;
        float4 aF = make_float4(0, 0, 0, 0), aG = make_float4(0, 0, 0, 0);
#pragma unroll
        for (int kk = 0; kk < 8; ++kk) {
          float pv = PASTP[l * 128 + 8 * ks + kk];
          float4 wf = wfp[kk * 32];
          float4 wg = wgp[kk * 32];
          aF.x += pv * wf.x; aF.y += pv * wf.y; aF.z += pv * wf.z; aF.w += pv * wf.w;
          aG.x += pv * wg.x; aG.y += pv * wg.y; aG.z += pv * wg.z; aG.w += pv * wg.w;
        }
        *(float4*)&REDF[ks * 132 + 4 * j4] = aF;
        *(float4*)&REDG[ks * 132 + 4 * j4] = aG;
        __syncthreads();
        if (tid < C) {
          float F = BFP[l * C + tid], G = BGP[l * C + tid];
#pragma unroll
          for (int r = 0; r < 16; ++r) { F += REDF[r * 132 + tid]; G += REDG[r * 132 + tid]; }
          aStore64(&P[((par * 10 + l) * 2 + 0) * 128 + tid], packF(F, tg));
          aStore64(&P[((par * 10 + l) * 2 + 1) * 128 + tid], packF(G, tg));
        }
        __syncthreads();
      }
    }
    return;
  }

  // =========================== S-HELPER (all 10 skip layers) ===================
  {
    const int j4b = tid & 63, ksb = tid >> 6;
    for (int s = 0; s < nsteps - 1; ++s) {
      const unsigned tg = (unsigned)(s + 1);
      const int par = s & 1;
      float4 acc = make_float4(0, 0, 0, 0);
#pragma unroll
      for (int l = 0; l < NL; ++l) {
        if (tid < C) {
          const ull* zp = &zpub[l * 128 + tid];
          ull v = aLoad64(zp);
          while ((unsigned)v != tg) v = aLoad64(zp);
          ZSH[tid] = unpackF(v);
        }
        __syncthreads();
        const float4* Ws4 = (const float4*)(Wskip + (size_t)l * C * CS);
#pragma unroll
        for (int kk = 0; kk < 16; ++kk) {
          float zv = ZSH[16 * ksb + kk];
          float4 w = Ws4[(size_t)(16 * ksb + kk) * 64 + j4b];
          acc.x += zv * w.x; acc.y += zv * w.y; acc.z += zv * w.z; acc.w += zv * w.w;
        }
        __syncthreads();
      }
      *(float4*)&REDF[ksb * 260 + 4 * j4b] = acc;
      __syncthreads();
      if (tid < CS) {
        float v = 0.f;
#pragma unroll
        for (int r = 0; r < 8; ++r) v += REDF[r * 260 + tid];
        aStore64(&skpart[(size_t)par * 256 + tid], packF(v, tg));
      }
      __syncthreads();
    }
    return;
  }
}

// ---------------- host launcher ---------------------------------------------------
extern "C" void kernel_launch(void* const* d_in, const int* in_sizes, int n_in,
                              void* d_out, int out_size, void* d_ws, size_t ws_size,
                              hipStream_t stream) {
  const int* prompt = (const int*)d_in[0];
  const float* E    = (const float*)d_in[2];
  const float* Wf   = (const float*)d_in[3];
  const float* Wg   = (const float*)d_in[4];
  const float* bf   = (const float*)d_in[5];
  const float* bg   = (const float*)d_in[6];
  const float* Wres = (const float*)d_in[7];
  const float* bres = (const float*)d_in[8];
  const float* Wskip= (const float*)d_in[9];
  const float* bskip= (const float*)d_in[10];
  const float* Wo1  = (const float*)d_in[11];
  const float* bo1  = (const float*)d_in[12];
  const float* Wo2  = (const float*)d_in[13];
  const float* bo2  = (const float*)d_in[14];
  int* dout = (int*)d_out;
  int ostride = out_size / NB;

  char* ws = (char*)d_ws;
  float* X0    = (float*)ws;                    // 16,777,216 B (reused for deint W)
  float* X1    = (float*)(ws + 16777216);       // 16,777,216 B
  ull* rings   = (ull*)(ws + 33554432);         // 33,521,664 B
  float* zlast = (float*)(ws + 67076096);       // 163,840 B
  char* chst   = ws + 67239936;                 // 4,194,304 B -> ends 71,434,240
  // deinterleaved taps live in X0's region (dead after the prompt layers):
  float* Wf0c  = (float*)ws;                    // 163,840 floats each
  float* Wf1c  = Wf0c + 163840;
  float* Wg0c  = Wf1c + 163840;
  float* Wg1c  = Wg0c + 163840;

  k_embed<<<1024, 256, 0, stream>>>(prompt, E, X0);
  float* xa = X0;
  float* xb = X1;
  for (int l = 0; l < NL; ++l) {
    k_layer<<<256, 256, 0, stream>>>(xa, xb, Wf, Wg, bf, bg, Wres, bres, rings, zlast, l);
    float* t = xa; xa = xb; xb = t;
  }
  k_head0<<<NB, 256, 0, stream>>>(zlast, Wskip, bskip, Wo1, bo1, Wo2, bo2, chst, dout, ostride);
  k_copyprompt<<<128, 256, 0, stream>>>(prompt, dout, ostride);
  k_deint<<<640, 256, 0, stream>>>(Wf, Wg, Wf0c, Wf1c, Wg0c, Wg1c);
  k_decode<<<256, NTHR, 0, stream>>>(E, Wf1c, Wg1c, Wf0c, Wg0c, bf, bg, Wres, bres,
                                     Wskip, bskip, Wo1, bo1, Wo2, bo2, rings, chst,
                                     dout, ostride);
}